// Round 7
// baseline (232.734 us; speedup 1.0000x reference)
//
#include <hip/hip_runtime.h>

typedef __attribute__((ext_vector_type(8))) short short8;
typedef __attribute__((ext_vector_type(4))) float f32x4;
union frag_u { short8 v; unsigned short u[8]; };

__device__ __forceinline__ float bf2f(unsigned short b) {
  unsigned int u = ((unsigned int)b) << 16;
  float f; __builtin_memcpy(&f, &u, 4); return f;
}
__device__ __forceinline__ unsigned short f2bf(float f) {
  unsigned int u; __builtin_memcpy(&u, &f, 4);
  return (unsigned short)((u + 0x7FFFu + ((u >> 16) & 1u)) >> 16);
}
__device__ __forceinline__ unsigned short hi_of(float f) { return f2bf(f); }
__device__ __forceinline__ unsigned short lo_of(float f) {
  unsigned short h = f2bf(f); return f2bf(f - bf2f(h));
}
__device__ __forceinline__ float sigm(float x) {
  return __builtin_amdgcn_rcpf(1.f + __expf(-x));
}
__device__ __forceinline__ float tanh_(float x) {
  return 1.f - 2.f * __builtin_amdgcn_rcpf(1.f + __expf(2.f * x));
}

// DPP quad-perm lane exchange within 4-lane groups (full-rate VALU, no LDS).
// 0xB1 = [1,0,3,2] (xor-1), 0x4E = [2,3,0,1] (xor-2).
__device__ __forceinline__ float dpp_xor1(float x) {
  union { float f; int i; } a, r; a.f = x;
  r.i = __builtin_amdgcn_update_dpp(0, a.i, 0xB1, 0xF, 0xF, true);
  return r.f;
}
__device__ __forceinline__ float dpp_xor2(float x) {
  union { float f; int i; } a, r; a.f = x;
  r.i = __builtin_amdgcn_update_dpp(0, a.i, 0x4E, 0xF, 0xF, true);
  return r.f;
}

// Fallback dtype detector (parallel): even-indexed uint16s of an f32 buffer
// are mantissa halves (insane bf16 exponents); of a bf16 buffer they are
// N(0,1) values (exponents 100..140). flag: 0 = bf16, 1 = f32.
__global__ void detect_dtype_kernel(const unsigned short* s, int* flag) {
  int i = threadIdx.x;   // 64 threads
  unsigned short v = s[2 * i];
  int e = (v >> 7) & 0xFF;
  unsigned long long m = __ballot(e < 100 || e > 140);
  if (i == 0) *flag = (__popcll(m) >= 16) ? 1 : 0;
}

// sA(16 x Kpad bf16, stride AS) @ W(K x N) -> sG[n][m]  (G stride 20)
// A-frag: lane holds A[m=lane&15][k=kc*32+quad*8+j]; B-frag: W[k][n=tile*16+(lane&15)]
// C/D: row m = quad*4+reg, col n = lane&15   [verified m89/m91]
// 16 waves: tiles strided by 16.
template <int AS, typename GetB, typename GetW>
__device__ __forceinline__ void mfma_layer(const unsigned short* sA, float* sG,
    int wave, int col, int quad, int kc_n, int ntiles, int N, GetB getb, GetW getw)
{
  for (int tile = wave; tile < ntiles; tile += 16) {
    int n = tile * 16 + col;
    float b = (n < N) ? getb(n) : 0.f;
    f32x4 acc = {b, b, b, b};
    for (int kc = 0; kc < kc_n; ++kc) {
      short8 a = *(const short8*)&sA[col * AS + kc * 32 + quad * 8];
      frag_u w;
      #pragma unroll
      for (int j = 0; j < 8; ++j) {
        int k = kc * 32 + quad * 8 + j;
        w.u[j] = (n < N) ? getw(k, n) : (unsigned short)0;
      }
      acc = __builtin_amdgcn_mfma_f32_16x16x32_bf16(a, w.v, acc, 0, 0, 0);
    }
    *(f32x4*)&sG[n * 20 + quad * 4] = acc;
  }
}

// relu(sG col) -> sA as bf16 hi at [0,N), optional lo at [loOff,loOff+N), zero pad to Kpad
template <int AS, bool LO>
__device__ __forceinline__ void relu_fill(const float* sG, unsigned short* sA,
                                          int tid, int N, int loOff, int Kpad) {
  for (int idx = tid; idx < 16 * Kpad; idx += 1024) {
    int m = idx & 15, n = idx >> 4;
    unsigned short v = 0;
    if (n < N) {
      v = f2bf(fmaxf(sG[n * 20 + m], 0.f));
    } else if (LO && n >= loOff && n < loOff + N) {
      float x = fmaxf(sG[(n - loOff) * 20 + m], 0.f);
      v = lo_of(x);
    }
    sA[m * AS + n] = v;
  }
}

// 1024 threads / 16 waves, 16 rows per block, grid = 512.
// SINGLE-PHASE LSTM with IN-REGISTER gate transpose:
// weight columns are gate-permuted (n_new = u*4+gate). Wave w's MFMA acc
// holds, per 4-lane quad-group {col=c0*4+g}, the 4 gates g of item
// u = w*4+c0 for rows m = quad*4+0..3. A 2-stage DPP quad-perm butterfly
// (xor-1, xor-2) transposes this 4x4 entirely in VGPRs, so each lane ends
// with all 4 gates of its item (m = quad*4+(col&3), u = w*4+(col>>2)).
// -> the sG LDS round-trip (b128 write + 4 dependent b32 reads, ~250cy
// latency + most bank conflicts) is GONE from the recurrence. One barrier
// per step; sG only used by the tail MLP. Waves 13..15 feed x.
template <bool F32>
__global__ __launch_bounds__(1024, 8) void value_net_kernel(
    const void* state_, const void* wih_, const void* whh_,
    const void* bih_, const void* bhh_,
    const void* w1_, const void* b1_, const void* w2_, const void* b2_,
    const void* w3_, const void* b3_, const void* w4_, const void* b4_,
    void* out_, const int* flag)
{
  if (flag && *flag != (F32 ? 1 : 0)) return;   // fallback path: other variant runs

  // A column layout, LSTM phase:
  //  bf16: [x(0..6) | h_hi(7..56) | h_lo(57..106) | 0-pad..127]           K=4x32
  //  f32 : [x_hi(0..6) | x_lo(7..13) | x_hi(14..20) | h_hi(21..70) |
  //         h_lo(71..120) | h_hi(121..170) | 0-pad..191]                  K=6x32
  //        paired with W rows [Wx_hi|Wx_hi|Wx_lo|Wh_hi|Wh_hi|Wh_lo] (tri-product)
  constexpr int AS = F32 ? 328 : 168;   // max Kpad (+8 pad): f32 L2 needs 320
  constexpr int KC = F32 ? 6 : 4;

  __shared__ __align__(16) unsigned short sA[2][16 * AS];  // double-buffered
  __shared__ __align__(16) float sG[208 * 20];             // tail MLP only

  const unsigned short* st16 = (const unsigned short*)state_;
  const float*          stf  = (const float*)state_;

  const int tid  = threadIdx.x;
  const int wave = tid >> 6;            // 0..15
  const int lane = tid & 63;
  const int col  = lane & 15;
  const int quad = lane >> 4;
  const int r0   = blockIdx.x * 16;

  // ---- zero BOTH sA buffers (h0 = 0 and all K padding) ----
  {
    unsigned int* a32 = (unsigned int*)&sA[0][0];
    constexpr int ZT = 16 * AS;        // uints across both buffers
    #pragma unroll
    for (int i = 0; i < (ZT + 1023) / 1024; ++i) {
      int idx = tid + i * 1024;
      if (idx < ZT) a32[idx] = 0;
    }
  }

  // ---- LSTM weight getter (n is ORIGINAL column index) ----
  auto W_lstm = [&](int k, int n) -> unsigned short {
    if constexpr (!F32) {
      const unsigned short* wih = (const unsigned short*)wih_;
      const unsigned short* whh = (const unsigned short*)whh_;
      if (k < 7)   return wih[k * 200 + n];
      if (k < 57)  return whh[(k - 7) * 200 + n];
      if (k < 107) return whh[(k - 57) * 200 + n];
      return (unsigned short)0;
    } else {
      const float* wih = (const float*)wih_;
      const float* whh = (const float*)whh_;
      if (k < 7)   return hi_of(wih[k * 200 + n]);
      if (k < 14)  return hi_of(wih[(k - 7) * 200 + n]);
      if (k < 21)  return lo_of(wih[(k - 14) * 200 + n]);
      if (k < 71)  return hi_of(whh[(k - 21) * 200 + n]);
      if (k < 121) return hi_of(whh[(k - 71) * 200 + n]);
      if (k < 171) return lo_of(whh[(k - 121) * 200 + n]);
      return (unsigned short)0;
    }
  };
  auto ldf = [&](const void* p, int i) -> float {
    if constexpr (F32) return ((const float*)p)[i];
    else               return bf2f(((const unsigned short*)p)[i]);
  };

  // ---- persistent LSTM weight fragments: 13 gate-permuted N-tiles ----
  const bool hasTile = (wave < 13);
  frag_u wf[KC];
  float  wb = 0.f;
  if (hasTile) {
    int nn = wave * 16 + col;                              // permuted col
    int no = (nn < 200) ? ((nn & 3) * 50 + (nn >> 2)) : 0; // original col
    #pragma unroll
    for (int kc = 0; kc < KC; ++kc) {
      #pragma unroll
      for (int j = 0; j < 8; ++j) {
        int k = kc * 32 + quad * 8 + j;
        wf[kc].u[j] = (nn < 200) ? W_lstm(k, no) : (unsigned short)0;
      }
    }
    wb = (nn < 200) ? (ldf(bih_, no) + ldf(bhh_, no)) : 0.f;
  }

  // per-lane LSTM item after DPP transpose: (m = quad*4+(col&3), u = wave*4+(col>>2))
  const int  u_   = wave * 4 + (col >> 2);
  const int  mm   = quad * 4 + (col & 3);
  const bool iact = hasTile && (u_ < 50);
  float c_ = 0.f, hf = 0.f;

  // ---- x-feed: waves 13..15, threads 832..943 (16 rows x 7 dims) ----
  const bool isx = (tid >= 832) && (tid < 944);
  const int  xm = (tid - 832) / 7, xd = (tid - 832) - ((tid - 832) / 7) * 7;
  auto xgidx = [&](int t) -> size_t { return (size_t)(r0 + xm) * 832 + t * 13 + 6 + xd; };
  auto xwrite = [&](unsigned short* sAw, float fv, unsigned short bv) {
    if constexpr (!F32) { sAw[xm * AS + xd] = bv; }
    else {
      unsigned short h = f2bf(fv);
      sAw[xm * AS + xd] = h; sAw[xm * AS + 14 + xd] = h;
      sAw[xm * AS + 7 + xd] = f2bf(fv - bf2f(h));
    }
  };
  unsigned short xv16 = 0; float xvf = 0.f;   // prefetched x_{t+1}

  __syncthreads();
  if (isx) {   // x_0 into buf0 + prefetch x_1
    if constexpr (!F32) { xwrite(&sA[0][0], 0.f, st16[xgidx(0)]); xv16 = st16[xgidx(1)]; }
    else                { xwrite(&sA[0][0], stf[xgidx(0)], 0);    xvf  = stf[xgidx(1)]; }
  }
  __syncthreads();

  // ---- LSTM: 64 steps, ONE barrier per step, no LDS gate round-trip ----
  for (int t = 0; t < 64; ++t) {
    const unsigned short* sAr = &sA[t & 1][0];
    unsigned short*       sAw = &sA[(t & 1) ^ 1][0];

    if (hasTile) {
      short8 a[KC];
      #pragma unroll
      for (int kc = 0; kc < KC; ++kc)
        a[kc] = *(const short8*)&sAr[col * AS + kc * 32 + quad * 8];
      f32x4 acc = {wb, wb, wb, wb};
      #pragma unroll
      for (int kc = 0; kc < KC; ++kc)
        acc = __builtin_amdgcn_mfma_f32_16x16x32_bf16(a[kc], wf[kc].v, acc, 0, 0, 0);

      // 4x4 in-register transpose across the xor-4 lane group (DPP):
      // in : lane g of quad-group holds gate_g for rows m=quad*4+0..3
      // out: lane j holds all 4 gates (i,f,g,o) of row m=quad*4+j
      f32x4 s1, m1, s2, w;
      #pragma unroll
      for (int r = 0; r < 4; ++r) s1[r] = dpp_xor1(acc[r]);
      const bool b0 = (lane & 1);
      m1[0] = b0 ? s1[1] : acc[0];
      m1[1] = b0 ? acc[1] : s1[0];
      m1[2] = b0 ? s1[3] : acc[2];
      m1[3] = b0 ? acc[3] : s1[2];
      #pragma unroll
      for (int r = 0; r < 4; ++r) s2[r] = dpp_xor2(m1[r]);
      const bool b1 = (lane & 2);
      w[0] = b1 ? s2[2] : m1[0];   // i
      w[1] = b1 ? s2[3] : m1[1];   // f
      w[2] = b1 ? m1[2] : s2[0];   // g
      w[3] = b1 ? m1[3] : s2[1];   // o

      if (iact) {
        float cc = sigm(w[1]) * c_ + sigm(w[0]) * tanh_(w[2]);
        c_ = cc;
        float h = sigm(w[3]) * tanh_(cc);
        if (t < 63) {
          unsigned short hb = f2bf(h);
          unsigned short hl = f2bf(h - bf2f(hb));
          if constexpr (!F32) {
            sAw[mm * AS + 7 + u_] = hb; sAw[mm * AS + 57 + u_] = hl;
          } else {
            sAw[mm * AS + 21 + u_] = hb; sAw[mm * AS + 121 + u_] = hb;
            sAw[mm * AS + 71 + u_] = hl;
          }
        } else hf = h;
      }
    } else if (isx && t < 63) {
      if constexpr (!F32) xwrite(sAw, 0.f, xv16); else xwrite(sAw, xvf, 0);
      if (t < 62) { if constexpr (!F32) xv16 = st16[xgidx(t + 2)]; else xvf = stf[xgidx(t + 2)]; }
    }
    __syncthreads();
  }

  // ---- tail MLP, fused (uses sA[0]) ----
  // joint cols: bf16 [self(0..5)|h_hi(6..55)|h_lo(56..105)] K=106->128
  //             f32  [self_hi(0..5)|h_hi(6..55)|self_lo(56..61)|h_lo(62..111)] K=112->128
  unsigned short* sA0 = &sA[0][0];
  {
    unsigned int* a32 = (unsigned int*)sA0;
    #pragma unroll
    for (int i = 0; i < (16 * AS / 2 + 1023) / 1024; ++i) {
      int idx = tid + i * 1024;
      if (idx < 16 * AS / 2) a32[idx] = 0;
    }
  }
  __syncthreads();
  if (iact) {
    unsigned short hb = f2bf(hf);
    unsigned short hl = f2bf(hf - bf2f(hb));
    sA0[mm * AS + 6 + u_] = hb;
    if constexpr (!F32) sA0[mm * AS + 56 + u_] = hl; else sA0[mm * AS + 62 + u_] = hl;
  }
  if (tid < 96) {
    int m = tid / 6, d = tid - (tid / 6) * 6;
    if constexpr (!F32) sA0[m * AS + d] = st16[(size_t)(r0 + m) * 832 + d];
    else {
      float f = stf[(size_t)(r0 + m) * 832 + d];
      sA0[m * AS + d] = hi_of(f); sA0[m * AS + 56 + d] = lo_of(f);
    }
  }
  __syncthreads();

  // L1: -> 150
  mfma_layer<AS>(sA0, sG, wave, col, quad, 4, 10, 150,
    [&](int n) { return ldf(b1_, n); },
    [&](int k, int n) -> unsigned short {
      if constexpr (!F32) {
        const unsigned short* w1 = (const unsigned short*)w1_;
        if (k < 56)  return w1[k * 150 + n];
        if (k < 106) return w1[(k - 50) * 150 + n];
        return (unsigned short)0;
      } else {
        const float* w1 = (const float*)w1_;
        if (k < 56)  return hi_of(w1[k * 150 + n]);
        if (k < 112) return hi_of(w1[(k - 56) * 150 + n]);
        return (unsigned short)0;
      }
    });
  __syncthreads();
  if constexpr (!F32) relu_fill<AS, false>(sG, sA0, tid, 150, 160, 160);
  else                relu_fill<AS, true >(sG, sA0, tid, 150, 150, 320);
  __syncthreads();

  // L2: 150 -> 100
  mfma_layer<AS>(sA0, sG, wave, col, quad, F32 ? 10 : 5, 7, 100,
    [&](int n) { return ldf(b2_, n); },
    [&](int k, int n) -> unsigned short {
      if constexpr (!F32) {
        const unsigned short* w2 = (const unsigned short*)w2_;
        return (k < 150) ? w2[k * 100 + n] : (unsigned short)0;
      } else {
        const float* w2 = (const float*)w2_;
        if (k < 150) return hi_of(w2[k * 100 + n]);
        if (k < 300) return hi_of(w2[(k - 150) * 100 + n]);
        return (unsigned short)0;
      }
    });
  __syncthreads();
  if constexpr (!F32) relu_fill<AS, false>(sG, sA0, tid, 100, 128, 128);
  else                relu_fill<AS, true >(sG, sA0, tid, 100, 100, 224);
  __syncthreads();

  // L3: 100 -> 100
  mfma_layer<AS>(sA0, sG, wave, col, quad, F32 ? 7 : 4, 7, 100,
    [&](int n) { return ldf(b3_, n); },
    [&](int k, int n) -> unsigned short {
      if constexpr (!F32) {
        const unsigned short* w3 = (const unsigned short*)w3_;
        return (k < 100) ? w3[k * 100 + n] : (unsigned short)0;
      } else {
        const float* w3 = (const float*)w3_;
        if (k < 100) return hi_of(w3[k * 100 + n]);
        if (k < 200) return hi_of(w3[(k - 100) * 100 + n]);
        return (unsigned short)0;
      }
    });
  __syncthreads();

  // L4: relu(sG) @ w4 + b4, f32 VALU, 16-lane shuffle reduce (first 256 threads)
  if (tid < 256) {
    int m = tid >> 4, j0 = tid & 15;
    float s = 0.f;
    for (int j = j0; j < 100; j += 16)
      s += fmaxf(sG[j * 20 + m], 0.f) * ldf(w4_, j);
    s += __shfl_xor(s, 8); s += __shfl_xor(s, 4);
    s += __shfl_xor(s, 2); s += __shfl_xor(s, 1);
    if (j0 == 0) {
      float v = s + ldf(b4_, 0);
      if constexpr (!F32) ((unsigned short*)out_)[r0 + m] = f2bf(v);
      else                ((float*)out_)[r0 + m] = v;
    }
  }
}

extern "C" void kernel_launch(void* const* d_in, const int* in_sizes, int n_in,
                              void* d_out, int out_size, void* d_ws, size_t ws_size,
                              hipStream_t stream) {
  (void)n_in; (void)out_size;
  // d_in[1..10] (mlp1_* / attn_*) are dead code in the reference — unused.
  const void* state = d_in[0];
  const void* wih = d_in[11]; const void* whh = d_in[12];
  const void* bih = d_in[13]; const void* bhh = d_in[14];
  const void* w1  = d_in[15]; const void* b1  = d_in[16];
  const void* w2  = d_in[17]; const void* b2  = d_in[18];
  const void* w3  = d_in[19]; const void* b3  = d_in[20];
  const void* w4  = d_in[21]; const void* b4  = d_in[22];

  // Host-side dtype selection from the state buffer byte size: one launch,
  // no detect kernel, no dead-variant dispatch.
  const long long F32B  = 8192LL * 64 * 13 * 4;
  const long long BF16B = 8192LL * 64 * 13 * 2;
  long long sz = in_sizes ? (long long)in_sizes[0] : -1;

  if (sz == F32B) {
    value_net_kernel<true><<<dim3(512), dim3(1024), 0, stream>>>(
        state, wih, whh, bih, bhh, w1, b1, w2, b2, w3, b3, w4, b4, d_out,
        (const int*)nullptr);
  } else if (sz == BF16B) {
    value_net_kernel<false><<<dim3(512), dim3(1024), 0, stream>>>(
        state, wih, whh, bih, bhh, w1, b1, w2, b2, w3, b3, w4, b4, d_out,
        (const int*)nullptr);
  } else if (ws_size >= sizeof(int)) {
    // Fallback: on-device detect + both variants (one exits immediately).
    int* flag = (int*)d_ws;
    detect_dtype_kernel<<<dim3(1), dim3(64), 0, stream>>>(
        (const unsigned short*)state, flag);
    value_net_kernel<false><<<dim3(512), dim3(1024), 0, stream>>>(
        state, wih, whh, bih, bhh, w1, b1, w2, b2, w3, b3, w4, b4, d_out, flag);
    value_net_kernel<true><<<dim3(512), dim3(1024), 0, stream>>>(
        state, wih, whh, bih, bhh, w1, b1, w2, b2, w3, b3, w4, b4, d_out, flag);
  } else {
    value_net_kernel<false><<<dim3(512), dim3(1024), 0, stream>>>(
        state, wih, whh, bih, bhh, w1, b1, w2, b2, w3, b3, w4, b4, d_out,
        (const int*)nullptr);
  }
}